// Round 9
// baseline (422.847 us; speedup 1.0000x reference)
//
#include <hip/hip_runtime.h>
#include <hip/hip_bf16.h>

#define THREADS 256
#define HP 136     // padded LDS row stride (shorts) for h rows

typedef float f32x4 __attribute__((ext_vector_type(4)));
typedef short s16x8 __attribute__((ext_vector_type(8)));

static __device__ __forceinline__ short f2b(float x) {
    return __builtin_bit_cast(short, __float2bfloat16(x));
}
static __device__ __forceinline__ float b2f(short u) {
    unsigned int v = ((unsigned int)(unsigned short)u) << 16;
    return __builtin_bit_cast(float, v);
}
static __device__ __forceinline__ void split8(const f32x4 a, const f32x4 b, s16x8& hi, s16x8& lo) {
    #pragma unroll
    for (int j = 0; j < 4; ++j) {
        short h0 = f2b(a[j]); hi[j]   = h0; lo[j]   = f2b(a[j] - b2f(h0));
        short h1 = f2b(b[j]); hi[j+4] = h1; lo[j+4] = f2b(b[j] - b2f(h1));
    }
}
static __device__ __forceinline__ s16x8 cvt8(const f32x4 a, const f32x4 b) {
    s16x8 r;
    r[0]=f2b(a[0]); r[1]=f2b(a[1]); r[2]=f2b(a[2]); r[3]=f2b(a[3]);
    r[4]=f2b(b[0]); r[5]=f2b(b[1]); r[6]=f2b(b[2]); r[7]=f2b(b[3]);
    return r;
}
static __device__ __forceinline__ float sigm(float x) { return 1.0f / (1.0f + __expf(-x)); }

#define MFMA16(A,B,C) __builtin_amdgcn_mfma_f32_16x16x32_bf16((A),(B),(C),0,0,0)

// Raw barrier: retire this wave's LDS ops; leave global prefetches in flight.
#define RAWBAR() do {                                               \
    asm volatile("s_waitcnt lgkmcnt(0)" ::: "memory");              \
    __builtin_amdgcn_s_barrier();                                   \
    asm volatile("" ::: "memory"); } while (0)

// ---- pre-pass: build XOR-swizzled hi/lo weight image + W2 bf16 ---------------
// image (shorts): chunk cp (32 KB): [fz][plane][n][slot*8], slot = kg ^ ((n>>1)&3)
// 32 chunks * 16384 shorts = 524288 (1 MB); then W2 bf16 [128][128] = 16384.
__global__ __launch_bounds__(256) void itemfusing_prep(
    const float* __restrict__ Wf1, const float* __restrict__ Wf2,
    const float* __restrict__ W2, short* __restrict__ wsp)
{
    const int t = blockIdx.x * 256 + threadIdx.x;
    if (t < 65536) {
        const int kg = t & 3;
        const int n  = (t >> 2) & 127;
        const int pl = (t >> 9) & 1;
        const int cp = (t >> 10) & 31;
        const int fz = (t >> 15) & 1;
        const float* src = (fz ? Wf2 : Wf1) + (size_t)n * 1024 + cp * 32 + kg * 8;
        s16x8 hi, lo; split8(*(const f32x4*)src, *(const f32x4*)(src + 4), hi, lo);
        const int slot = kg ^ ((n >> 1) & 3);
        *(s16x8*)(wsp + (size_t)cp * 16384 + fz * 8192 + pl * 4096 + n * 32 + slot * 8)
            = pl ? lo : hi;
    } else if (t < 65536 + 2048) {
        const int i = (t - 65536) * 8;
        const float* src = W2 + i;
        *(s16x8*)(wsp + 524288 + i) = cvt8(*(const f32x4*)src, *(const f32x4*)(src + 4));
    }
}

// ---- main: 256 thr, 4 waves = (session s, m-tile mt); M=16/wave, both weights.
// R7's staging (image reg-copy, XOR slot, raw barriers) at R3's geometry
// (3 blocks/CU). acc = 64 regs/wave.
__global__ __launch_bounds__(THREADS, 3) void itemfusing_main(
    const float* __restrict__ inter, const float* __restrict__ intra,
    const float* __restrict__ bf1, const float* __restrict__ bf2,
    const float* __restrict__ W1,  const float* __restrict__ b1,
    const float* __restrict__ b2,
    const float* __restrict__ qw,  const float* __restrict__ qb,
    const float* __restrict__ W3,  const float* __restrict__ b3,
    const short* __restrict__ gimg, const short* __restrict__ w2b,
    float* __restrict__ out)
{
    __shared__ union {
        short wbuf[2][2][128][32];   // [buf][plane][n][slot] : 32768 B
        short hbuf[2][32][HP];       // h rows for 2 sessions : 17408 B
    } u;
    __shared__ float vn  [2][128];   // 1024 B
    __shared__ float w1v [2][128];   // 1024 B
    __shared__ float sglp[2][2][128];// 2048 B   -> static total 36864 B

    const int tid = threadIdx.x;
    const int l   = tid & 63;
    const int l15 = l & 15;
    const int kg  = l >> 4;
    const int w   = tid >> 6;     // 0..3
    const int s   = w >> 1;       // session slot in block (0..1)
    const int mt  = w & 1;        // m-tile within session (16 rows)
    const int sess = blockIdx.x * 2 + s;
    const int arow = sess * 32 + mt * 16 + l15;
    const int slot8 = (kg ^ ((l15 >> 1) & 3)) * 8;

    const float* A1 = inter + (size_t)arow * 1024 + kg * 8;
    const float* A2 = intra + (size_t)arow * 1024 + kg * 8;
    short* wb = &u.wbuf[0][0][0][0];

    f32x4 acc1[8], acc2[8];
    #pragma unroll
    for (int nt = 0; nt < 8; ++nt) {
        acc1[nt] = f32x4{0.f,0.f,0.f,0.f};
        acc2[nt] = f32x4{0.f,0.f,0.f,0.f};
    }

    // staging: each thread copies 32 shorts (64 B) of one 8192-short fz-chunk
    s16x8 wr0, wr1, wr2, wr3;
#define WLOADR(FZ, CP) do {                                                     \
    const short* p_ = gimg + (size_t)(CP) * 16384 + (FZ) * 8192 + tid * 32;     \
    wr0 = *(const s16x8*)p_;        wr1 = *(const s16x8*)(p_ + 8);              \
    wr2 = *(const s16x8*)(p_ + 16); wr3 = *(const s16x8*)(p_ + 24); } while (0)
#define WSTORE(BUF) do {                                                        \
    short* d_ = wb + (BUF) * 8192 + tid * 32;                                   \
    *(s16x8*)d_ = wr0;        *(s16x8*)(d_ + 8) = wr1;                          \
    *(s16x8*)(d_ + 16) = wr2; *(s16x8*)(d_ + 24) = wr3; } while (0)
#define ALOAD(R0, R1, AP, CP) do {                                             \
    const float* p_ = (AP) + (CP) * 32;                                        \
    R0 = *(const f32x4*)p_;  R1 = *(const f32x4*)(p_ + 4); } while (0)
#define COMPUTE(BUF, ACC, R0, R1) do {                                         \
    s16x8 ah, al; split8(R0, R1, ah, al);                                      \
    const short* fb_ = wb + (BUF) * 8192 + l15 * 32 + slot8;                   \
    _Pragma("unroll")                                                          \
    for (int nt_ = 0; nt_ < 8; ++nt_) {                                        \
        s16x8 bh_ = *(const s16x8*)(fb_ + nt_ * 512);                          \
        s16x8 bl_ = *(const s16x8*)(fb_ + 4096 + nt_ * 512);                   \
        ACC[nt_] = MFMA16(ah, bh_, ACC[nt_]);                                  \
        ACC[nt_] = MFMA16(al, bh_, ACC[nt_]);                                  \
        ACC[nt_] = MFMA16(ah, bl_, ACC[nt_]);                                  \
    } } while (0)

    f32x4 r1a, r1b;   // A(inter) regs
    f32x4 r2a, r2b;   // A(intra) regs

    // prologue: buf0 <- Wf1 c0; regs <- Wf2 c0; A regs <- c0
    WLOADR(0, 0); WSTORE(0);
    WLOADR(1, 0);
    ALOAD(r1a, r1b, A1, 0);
    ALOAD(r2a, r2b, A2, 0);
    RAWBAR();

    #pragma unroll 1
    for (int cp = 0; cp < 32; ++cp) {
        const bool more = (cp < 31);
        {   // EVEN: stage Wf2 cp -> buf1; prefetch Wf1 cp+1; compute acc1 from buf0
            WSTORE(1);
            if (more) WLOADR(0, cp + 1);
            COMPUTE(0, acc1, r1a, r1b);
            if (more) ALOAD(r1a, r1b, A1, cp + 1);
        }
        RAWBAR();
        {   // ODD: stage Wf1 cp+1 -> buf0; prefetch Wf2 cp+1; compute acc2 from buf1
            if (more) { WSTORE(0); WLOADR(1, cp + 1); }
            COMPUTE(1, acc2, r2a, r2b);
            if (more) ALOAD(r2a, r2b, A2, cp + 1);
        }
        RAWBAR();
    }
#undef WLOADR
#undef WSTORE
#undef ALOAD
#undef COMPUTE

    // ---------------- phase 2: bias + gate -> h (fp32, in acc1) ----------------
    #pragma unroll
    for (int nt = 0; nt < 8; ++nt) {
        const int n = nt * 16 + l15;
        const float bb1 = bf1[n], bb2 = bf2[n];
        #pragma unroll
        for (int rj = 0; rj < 4; ++rj) {
            float x1 = acc1[nt][rj] + bb1;
            float x2 = acc2[nt][rj] + bb2;
            float g  = sigm(x1 + x2);
            acc1[nt][rj] = x2 + g * (x1 - x2);
        }
    }

    // v_n (session row 31 lives in wave mt=1, kg=3, rj=3)
    if (mt == 1 && kg == 3) {
        #pragma unroll
        for (int nt = 0; nt < 8; ++nt) vn[s][nt * 16 + l15] = acc1[nt][3];
    }
    __syncthreads();   // B1: vn visible; wbuf reads all done (LDS becomes hbuf)

    // ---------------- phase 3: w1v = W1 @ v_n + b1 (1 output/thread) ----------
    {
        const int n = mt * 64 + l;
        const float* w1r = W1 + (size_t)n * 128;
        float acc = b1[n];
        #pragma unroll
        for (int kk = 0; kk < 128; kk += 4) {
            f32x4 vv = *(const f32x4*)&vn[s][kk];
            f32x4 u0 = *(const f32x4*)(w1r + kk);
            #pragma unroll
            for (int j = 0; j < 4; ++j) acc += u0[j] * vv[j];
        }
        w1v[s][n] = acc;
    }
    // h rows -> LDS bf16 (own 16 rows)
    short (*hb)[HP] = u.hbuf[s];
    #pragma unroll
    for (int nt = 0; nt < 8; ++nt)
        #pragma unroll
        for (int rj = 0; rj < 4; ++rj)
            hb[mt * 16 + kg * 4 + rj][nt * 16 + l15] = f2b(acc1[nt][rj]);
    __syncthreads();   // B2: w1v + hbuf visible

    // ---------------- phase 4: w2h = h @ W2^T (MFMA, K=128, own 16 rows) ------
    f32x4 aw[8];
    #pragma unroll
    for (int nt = 0; nt < 8; ++nt) aw[nt] = f32x4{0.f, 0.f, 0.f, 0.f};
    #pragma unroll
    for (int ks = 0; ks < 4; ++ks) {
        const int kl = ks * 32 + kg * 8;
        s16x8 ah = *(const s16x8*)&hb[mt * 16 + l15][kl];
        #pragma unroll
        for (int nt = 0; nt < 8; ++nt) {
            s16x8 bw = *(const s16x8*)&w2b[(size_t)(nt * 16 + l15) * 128 + kl];
            aw[nt] = MFMA16(ah, bw, aw[nt]);
        }
    }

    // ---------------- phase 5: alpha rows (wave-local) -------------------------
    float prt[4] = {0.f, 0.f, 0.f, 0.f};
    #pragma unroll
    for (int nt = 0; nt < 8; ++nt) {
        const int n = nt * 16 + l15;
        const float qn = qw[n], wv_ = w1v[s][n], bb = b2[n];
        #pragma unroll
        for (int rj = 0; rj < 4; ++rj)
            prt[rj] += qn * sigm(wv_ + aw[nt][rj] + bb);
    }
    const float qbias = qb[0];
    #pragma unroll
    for (int rj = 0; rj < 4; ++rj) {
        float v = prt[rj];
        v += __shfl_xor(v, 1); v += __shfl_xor(v, 2);
        v += __shfl_xor(v, 4); v += __shfl_xor(v, 8);
        prt[rj] = v + qbias;          // alpha for row mt*16 + kg*4 + rj
    }

    // ---------------- phase 6: s_g partial over own 16 rows --------------------
    #pragma unroll
    for (int nt = 0; nt < 8; ++nt) {
        float sgv = 0.f;
        #pragma unroll
        for (int rj = 0; rj < 4; ++rj) sgv += prt[rj] * acc1[nt][rj];
        sgv += __shfl_xor(sgv, 16);
        sgv += __shfl_xor(sgv, 32);
        if (l < 16) sglp[s][mt][nt * 16 + l15] = sgv;
    }
    __syncthreads();   // B3: sglp visible

    // ---------------- phase 7: out = W3 @ [v_n ; s_g] + b3 ---------------------
    {
        const int n = mt * 64 + l;
        const float* w3r = W3 + (size_t)n * 256;
        float o = b3[n];
        #pragma unroll
        for (int kk = 0; kk < 128; kk += 4) {
            f32x4 vv = *(const f32x4*)&vn[s][kk];
            f32x4 s0 = *(const f32x4*)&sglp[s][0][kk];
            f32x4 s1 = *(const f32x4*)&sglp[s][1][kk];
            f32x4 a0 = *(const f32x4*)(w3r + kk);
            f32x4 c0 = *(const f32x4*)(w3r + 128 + kk);
            #pragma unroll
            for (int j = 0; j < 4; ++j)
                o += a0[j] * vv[j] + c0[j] * (s0[j] + s1[j]);
        }
        out[(size_t)sess * 128 + n] = o;
    }
}

// ---- naive fallback (only if ws too small; correctness insurance) ------------
__global__ __launch_bounds__(128) void itemfusing_naive(
    const float* __restrict__ inter, const float* __restrict__ intra,
    const float* __restrict__ Wf1, const float* __restrict__ bf1,
    const float* __restrict__ Wf2, const float* __restrict__ bf2,
    const float* __restrict__ W1,  const float* __restrict__ b1,
    const float* __restrict__ W2,  const float* __restrict__ b2,
    const float* __restrict__ qw,  const float* __restrict__ qb,
    const float* __restrict__ W3,  const float* __restrict__ b3,
    float* __restrict__ out)
{
    __shared__ float h[32][128];
    __shared__ float vn[128], w1v[128], al[32], sg[128], red[128];
    const int n = threadIdx.x; const int sess = blockIdx.x;
    for (int t0 = 0; t0 < 32; ++t0) {
        const float* e1 = inter + (size_t)(sess * 32 + t0) * 1024;
        const float* e2 = intra + (size_t)(sess * 32 + t0) * 1024;
        const float* r1 = Wf1 + (size_t)n * 1024;
        const float* r2 = Wf2 + (size_t)n * 1024;
        float s1 = bf1[n], s2 = bf2[n];
        for (int k = 0; k < 1024; ++k) { s1 += e1[k] * r1[k]; s2 += e2[k] * r2[k]; }
        float g = sigm(s1 + s2);
        h[t0][n] = s2 + g * (s1 - s2);
    }
    __syncthreads();
    vn[n] = h[31][n];
    __syncthreads();
    { float a = b1[n]; const float* w1r = W1 + (size_t)n * 128;
      for (int k = 0; k < 128; ++k) a += w1r[k] * vn[k];
      w1v[n] = a; }
    __syncthreads();
    for (int t0 = 0; t0 < 32; ++t0) {
        float x = b2[n]; const float* w2r = W2 + (size_t)n * 128;
        for (int k = 0; k < 128; ++k) x += w2r[k] * h[t0][k];
        red[n] = qw[n] * sigm(w1v[n] + x); __syncthreads();
        for (int s_ = 64; s_ > 0; s_ >>= 1) { if (n < s_) red[n] += red[n + s_]; __syncthreads(); }
        if (n == 0) al[t0] = red[0] + qb[0];
        __syncthreads();
    }
    { float s = 0.f; for (int t0 = 0; t0 < 32; ++t0) s += al[t0] * h[t0][n];
      sg[n] = s; }
    __syncthreads();
    { float o = b3[n]; const float* w3r = W3 + (size_t)n * 256;
      for (int k = 0; k < 128; ++k) o += w3r[k] * vn[k] + w3r[128 + k] * sg[k];
      out[(size_t)sess * 128 + n] = o; }
}

extern "C" void kernel_launch(void* const* d_in, const int* in_sizes, int n_in,
                              void* d_out, int out_size, void* d_ws, size_t ws_size,
                              hipStream_t stream) {
    (void)n_in; (void)out_size;
    const float* inter = (const float*)d_in[0];
    const float* intra = (const float*)d_in[1];
    const float* Wf1   = (const float*)d_in[3];
    const float* bf1   = (const float*)d_in[4];
    const float* Wf2   = (const float*)d_in[5];
    const float* bf2   = (const float*)d_in[6];
    const float* W1    = (const float*)d_in[7];
    const float* b1    = (const float*)d_in[8];
    const float* W2    = (const float*)d_in[9];
    const float* b2    = (const float*)d_in[10];
    const float* qw    = (const float*)d_in[11];
    const float* qb    = (const float*)d_in[12];
    const float* W3    = (const float*)d_in[13];
    const float* b3    = (const float*)d_in[14];
    float* out = (float*)d_out;

    const int nsess = in_sizes[2];               // 4096
    const size_t WS_NEED = (size_t)(524288 + 16384) * sizeof(short);

    if (d_ws != nullptr && ws_size >= WS_NEED) {
        short* wsp = (short*)d_ws;
        itemfusing_prep<<<264, 256, 0, stream>>>(Wf1, Wf2, W2, wsp);
        itemfusing_main<<<nsess / 2, THREADS, 0, stream>>>(
            inter, intra, bf1, bf2, W1, b1, b2, qw, qb, W3, b3,
            wsp, wsp + 524288, out);
    } else {
        itemfusing_naive<<<nsess, 128, 0, stream>>>(
            inter, intra, Wf1, bf1, Wf2, bf2, W1, b1, W2, b2, qw, qb, W3, b3, out);
    }
}